// Round 2
// baseline (120.692 us; speedup 1.0000x reference)
//
#include <hip/hip_runtime.h>

// Residual_Binary — fully fused, LDS-free, barrier-free streaming kernel.
//
// Index algebra (byte index j in [0,8192), 13 bits):
//   swap:       j -> j ^ 4096
//   transpose2: result[i] = a[rotl13(i)]
// Composing both stages:
//   y[j]   = x[j] | f1_{j^4096}(x[j^4096]),  f1: v -> (v & A1)^K1, A1=b1, K1=(~w1)&b1
//   out[o] = y[q] & f2_{rotr13(q)^4096}(y[q^1]),  q = rotl13^2(o),
//            f2: v -> (v & M2)^C2, M2=~b2, C2=((~w2)&M2)|b2
// Thread t owns input elements [16t,16t+16) and [4096+16t, 4096+16t+16)
// (mutual swap partners). Its 8 output words are Ko = t+512a and t+256+512a,
// a=0..3, gathered as byte-lane a of a 4x4 byte transpose of its y words.
// Everything stays in registers; one pass over HBM.

constexpr int W = 8192;

static __device__ __forceinline__ unsigned perm(unsigned a, unsigned b, unsigned sel) {
    return __builtin_amdgcn_perm(a, b, sel);  // sel 0-3 -> b bytes, 4-7 -> a bytes
}

// pack low bytes of 4 int32 lanes (high bytes are 0 by construction)
static __device__ __forceinline__ unsigned pack4(uint4 v) {
    unsigned p1 = perm(v.y, v.x, 0x03030400u);  // [x.b0, y.b0, 0, 0]
    unsigned p2 = perm(v.w, v.z, 0x04000303u);  // [0, 0, z.b0, w.b0]
    return p1 | p2;
}

// 4x4 byte transpose: T[a] = [y0.b(a), y1.b(a), y2.b(a), y3.b(a)]
static __device__ __forceinline__ void transpose4(const unsigned y[4], unsigned T[4]) {
    unsigned ab01 = perm(y[1], y[0], 0x05010400u);  // [y0b0,y1b0,y0b1,y1b1]
    unsigned cd01 = perm(y[1], y[0], 0x07030602u);  // [y0b2,y1b2,y0b3,y1b3]
    unsigned ab23 = perm(y[3], y[2], 0x05010400u);
    unsigned cd23 = perm(y[3], y[2], 0x07030602u);
    T[0] = perm(ab23, ab01, 0x05040100u);
    T[1] = perm(ab23, ab01, 0x07060302u);
    T[2] = perm(cd23, cd01, 0x05040100u);
    T[3] = perm(cd23, cd01, 0x07060302u);
}

static __device__ __forceinline__ uint4 unpack4(unsigned p) {
    return make_uint4(p & 0xFFu, (p >> 8) & 0xFFu, (p >> 16) & 0xFFu, p >> 24);
}

__global__ __launch_bounds__(256)
void residual_binary_kernel(const int* __restrict__ x,
                            const int* __restrict__ w1, const int* __restrict__ w2,
                            const int* __restrict__ b1, const int* __restrict__ b2,
                            int* __restrict__ out, int rows_per_block)
{
    const int t  = threadIdx.x;       // t in [0,256)
    const int eA = 16 * t;            // side-A element base
    const int eB = 4096 + 16 * t;     // side-B element base (swap partner)

    // ---------------- row-invariant packed constants (once per block) -------
    unsigned A1A[4], K1A[4], A1B[4], K1B[4];
#pragma unroll
    for (int j = 0; j < 4; ++j) {
        uint4 lwA = *(const uint4*)(w1 + eA + 4 * j);
        uint4 lbA = *(const uint4*)(b1 + eA + 4 * j);
        uint4 lwB = *(const uint4*)(w1 + eB + 4 * j);
        uint4 lbB = *(const uint4*)(b1 + eB + 4 * j);
        A1A[j] = pack4(lbA);  K1A[j] = (~pack4(lwA)) & A1A[j];
        A1B[j] = pack4(lbB);  K1B[j] = (~pack4(lwB)) & A1B[j];
    }

    // stage-2 consts: for run base R, even-byte gather serves a in {0,1},
    // odd-byte gather serves a in {2,3}:
    //   side A: a=0,2 -> R=4096+8t ; a=1,3 -> R=8t
    //   side B: a=0,2 -> R=6144+8t ; a=1,3 -> R=2048+8t
    unsigned M2A[4], C2A[4], M2B[4], C2B[4];
    {
        const int runs[4] = { 4096 + 8 * t, 8 * t, 6144 + 8 * t, 2048 + 8 * t };
        unsigned* M2[4] = { M2A, M2A, M2B, M2B };
        unsigned* C2[4] = { C2A, C2A, C2B, C2B };
        const int aEven[4] = { 0, 1, 0, 1 };  // a index filled by even gather
#pragma unroll
        for (int k = 0; k < 4; ++k) {
            const int R = runs[k];
            unsigned pwlo = pack4(*(const uint4*)(w2 + R));
            unsigned pwhi = pack4(*(const uint4*)(w2 + R + 4));
            unsigned pblo = pack4(*(const uint4*)(b2 + R));
            unsigned pbhi = pack4(*(const uint4*)(b2 + R + 4));
            unsigned pbE = perm(pbhi, pblo, 0x06040200u);
            unsigned pwE = perm(pwhi, pwlo, 0x06040200u);
            unsigned pbO = perm(pbhi, pblo, 0x07050301u);
            unsigned pwO = perm(pwhi, pwlo, 0x07050301u);
            unsigned mE = ~pbE, mO = ~pbO;   // byte-wise ~ (all 32 bits packed)
            M2[k][aEven[k]]     = mE;  C2[k][aEven[k]]     = ((~pwE) & mE) | pbE;
            M2[k][aEven[k] + 2] = mO;  C2[k][aEven[k] + 2] = ((~pwO) & mO) | pbO;
        }
    }

    // ---------------- streaming row loop -----------------------------------
    long long row = (long long)blockIdx.x * rows_per_block;
    for (int r = 0; r < rows_per_block; ++r, ++row) {
        const int* xr = x + row * (long long)W;
        int*       orow = out + row * (long long)W;

        uint4 LA[4], LB[4];
#pragma unroll
        for (int j = 0; j < 4; ++j) {
            LA[j] = *(const uint4*)(xr + eA + 4 * j);
            LB[j] = *(const uint4*)(xr + eB + 4 * j);
        }

        unsigned XA[4], XB[4], YA[4], YB[4];
#pragma unroll
        for (int j = 0; j < 4; ++j) { XA[j] = pack4(LA[j]); XB[j] = pack4(LB[j]); }
#pragma unroll
        for (int j = 0; j < 4; ++j) {
            YA[j] = XA[j] | ((XB[j] & A1B[j]) ^ K1B[j]);
            YB[j] = XB[j] | ((XA[j] & A1A[j]) ^ K1A[j]);
        }

        unsigned TA[4], TB[4];
        transpose4(YA, TA);
        transpose4(YB, TB);

#pragma unroll
        for (int a = 0; a < 4; ++a) {
            unsigned oA = TA[a] & ((TA[a ^ 1] & M2A[a]) ^ C2A[a]);
            unsigned oB = TB[a] & ((TB[a ^ 1] & M2B[a]) ^ C2B[a]);
            *(uint4*)(orow + 2048 * a + 4 * t)        = unpack4(oA);
            *(uint4*)(orow + 1024 + 2048 * a + 4 * t) = unpack4(oB);
        }
    }
}

extern "C" void kernel_launch(void* const* d_in, const int* in_sizes, int n_in,
                              void* d_out, int out_size, void* d_ws, size_t ws_size,
                              hipStream_t stream) {
    const int* x  = (const int*)d_in[0];
    const int* w1 = (const int*)d_in[1];
    const int* w2 = (const int*)d_in[2];
    const int* b1 = (const int*)d_in[3];
    const int* b2 = (const int*)d_in[4];
    int* out = (int*)d_out;

    const int rows = in_sizes[0] / W;   // 8192
    const int RPB  = 4;
    const int grid = rows / RPB;        // 2048 blocks x 256 threads
    residual_binary_kernel<<<grid, 256, 0, stream>>>(x, w1, w2, b1, b2, out, RPB);
}

// Round 3
// 89.058 us; speedup vs baseline: 1.3552x; 1.3552x over previous
//
#include <hip/hip_runtime.h>

// Residual_Binary — fused single-pass kernel, LDS transpose staging,
// register prefetch, double-buffered Ts (2 barriers/row), NON-TEMPORAL stores.
//
// Identities (w1,w2,b1,b2 bytes in {0,255}):
//   z1 = (~(x^w1))&0xFF & b1 = (x & B1)^C1,  B1=b1, C1=(~w1)&b1
//   z2 = ((~(t^w2))&0xFF)|b2 = (t & M2)^C2,  M2=~b2, C2=((~w2)&~b2)|b2
//   swap: byte j -> j^4096 (packed word m -> m^1024)
//   transpose2 on packed words: one v_perm_b32 per output word.
// Output stream is write-once -> nontemporal stores keep the 256MiB out
// stream from evicting x (256MiB, re-read every replay) out of the LLC.

constexpr int W     = 8192;
constexpr int WORDS = 2048;
constexpr int HALF  = 1024;
constexpr int RPB   = 4;      // rows per block

typedef unsigned u32;
typedef u32 u32x4 __attribute__((ext_vector_type(4)));

static __device__ __forceinline__ u32 perm_b32(u32 hi, u32 lo, u32 sel) {
    return __builtin_amdgcn_perm(hi, lo, sel);
}

static __device__ __forceinline__ u32 pack4(uint4 v) {
    return (v.x & 0xFFu) | ((v.y & 0xFFu) << 8) | ((v.z & 0xFFu) << 16) | ((v.w & 0xFFu) << 24);
}

static __device__ __forceinline__ void nt_store4(int* p, u32 packed) {
    u32x4 v = { packed & 0xFFu, (packed >> 8) & 0xFFu,
                (packed >> 16) & 0xFFu, packed >> 24 };
    __builtin_nontemporal_store(v, (u32x4*)p);
}

__global__ __launch_bounds__(256)
void residual_binary_kernel(const int* __restrict__ x,
                            const int* __restrict__ w1, const int* __restrict__ w2,
                            const int* __restrict__ b1, const int* __restrict__ b2,
                            int* __restrict__ out)
{
    __shared__ u32 Xs[WORDS];
    __shared__ u32 Ts[2][WORDS];

    const int t = threadIdx.x;

    // --- per-thread packed constants (once per block) ---
    // stage-1 consts for swap-side words (2t+512q)^1024 (+1)
    u32 B1p[4][2], C1p[4][2], M2p[4][2], C2p[4][2];
#pragma unroll
    for (int q = 0; q < 4; ++q) {
        const int m = (2 * t + 512 * q) ^ HALF;
#pragma unroll
        for (int j = 0; j < 2; ++j) {
            const int e = 4 * (m + j);
            u32 pb1 = pack4(*(const uint4*)(b1 + e));
            u32 pw1 = pack4(*(const uint4*)(w1 + e));
            u32 pb2 = pack4(*(const uint4*)(b2 + e));
            u32 pw2 = pack4(*(const uint4*)(w2 + e));
            B1p[q][j] = pb1;
            C1p[q][j] = (~pw1) & pb1;
            M2p[q][j] = ~pb2;
            C2p[q][j] = ((~pw2) & (~pb2)) | pb2;
        }
    }

    const u32 sel_even = 0x06040200u;
    const u32 sel_odd  = 0x07050301u;

    const long long row0 = (long long)blockIdx.x * RPB;

    // prefetch row 0 into registers
    uint4 P[8];
    {
        const int* xr = x + row0 * (long long)W;
#pragma unroll
        for (int i = 0; i < 8; ++i)
            P[i] = *(const uint4*)(xr + 4 * (t + 256 * i));
    }

#pragma unroll
    for (int r = 0; r < RPB; ++r) {
        const int buf = r & 1;
        int* orow = out + (row0 + r) * (long long)W;

        // pack current row into Xs
#pragma unroll
        for (int i = 0; i < 8; ++i)
            Xs[t + 256 * i] = pack4(P[i]);

        // issue next row's global loads (cover latency with 2 barriers + 2 stages)
        if (r + 1 < RPB) {
            const int* xn = x + (row0 + r + 1) * (long long)W;
#pragma unroll
            for (int i = 0; i < 8; ++i)
                P[i] = *(const uint4*)(xn + 4 * (t + 256 * i));
        }

        __syncthreads();   // Xs ready

        // stage 1: y = x | swap(z1);  Ts[buf] = transpose2(y)
#pragma unroll
        for (int q = 0; q < 4; ++q) {
            const int m = 2 * t + 512 * q;
            uint2 xa = *(const uint2*)&Xs[m];
            uint2 xs = *(const uint2*)&Xs[m ^ HALF];
            u32 y0 = xa.x | ((xs.x & B1p[q][0]) ^ C1p[q][0]);
            u32 y1 = xa.y | ((xs.y & B1p[q][1]) ^ C1p[q][1]);
            const int K = t + 256 * q;
            Ts[buf][K]        = perm_b32(y1, y0, sel_even);
            Ts[buf][K + HALF] = perm_b32(y1, y0, sel_odd);
        }

        __syncthreads();   // Ts ready (also: all Xs reads of this row done)

        // stage 2: u = t & swap(z2);  out = transpose2(u), nt-store unpacked
#pragma unroll
        for (int q = 0; q < 4; ++q) {
            const int m = 2 * t + 512 * q;
            uint2 ta = *(const uint2*)&Ts[buf][m];
            uint2 ts = *(const uint2*)&Ts[buf][m ^ HALF];
            u32 u0 = ta.x & ((ts.x & M2p[q][0]) ^ C2p[q][0]);
            u32 u1 = ta.y & ((ts.y & M2p[q][1]) ^ C2p[q][1]);
            const int K = t + 256 * q;
            nt_store4(orow + 4 * K,          perm_b32(u1, u0, sel_even));
            nt_store4(orow + 4 * (K + HALF), perm_b32(u1, u0, sel_odd));
        }
        // no 3rd barrier: Ts is double-buffered; Xs writes of next row are
        // safe because this row's Xs reads completed before the 2nd barrier.
    }
}

extern "C" void kernel_launch(void* const* d_in, const int* in_sizes, int n_in,
                              void* d_out, int out_size, void* d_ws, size_t ws_size,
                              hipStream_t stream) {
    const int* x  = (const int*)d_in[0];
    const int* w1 = (const int*)d_in[1];
    const int* w2 = (const int*)d_in[2];
    const int* b1 = (const int*)d_in[3];
    const int* b2 = (const int*)d_in[4];
    int* out = (int*)d_out;

    const int rows = in_sizes[0] / W;   // 8192
    const int grid = rows / RPB;        // 2048 blocks x 256 threads
    residual_binary_kernel<<<grid, 256, 0, stream>>>(x, w1, w2, b1, b2, out);
}

// Round 4
// 85.324 us; speedup vs baseline: 1.4145x; 1.0438x over previous
//
#include <hip/hip_runtime.h>

// Residual_Binary — fused single-pass, thread-local stage 1, ONE barrier/row.
//
// Index algebra (byte j, 13 bits): swap j->j^4096 (packed word m -> m^1024);
// transpose2 = even/odd byte de-interleave = one v_perm_b32 per output word.
// Key: thread t owns words m = 2t+512q (q=0..3); m^1024 = 2t+512(q^2) is the
// SAME thread's word -> stage-1 swap+xnor is register-local. Only the second
// transpose needs a cross-thread exchange (Ts in LDS, double-buffered).
//
// Identities (w1,w2,b1,b2 bytes in {0,255}):
//   z1 = (~(x^w1))&0xFF & b1 = (x & B1)^C1,  B1=b1, C1=(~w1)&b1
//   z2 = ((~(t^w2))&0xFF)|b2 = (t & M2)^C2,  M2=~b2, C2=((~w2)&~b2)|b2
//
// LLC management: out (write-once) uses nontemporal stores; 25% of x rows
// (r==3) use nontemporal loads so the temporal 75% (192 MiB) fits the
// 256 MiB LLC with slack and stays resident across graph replays.

constexpr int W     = 8192;
constexpr int WORDS = 2048;
constexpr int HALF  = 1024;
constexpr int RPB   = 4;

typedef unsigned u32;
typedef u32 u32x4 __attribute__((ext_vector_type(4)));

static __device__ __forceinline__ u32 perm_b32(u32 hi, u32 lo, u32 sel) {
    return __builtin_amdgcn_perm(hi, lo, sel);
}

static __device__ __forceinline__ u32 pack4(u32x4 v) {
    return (v[0] & 0xFFu) | ((v[1] & 0xFFu) << 8) | ((v[2] & 0xFFu) << 16) | ((v[3] & 0xFFu) << 24);
}

static __device__ __forceinline__ void nt_store4(int* p, u32 packed) {
    u32x4 v = { packed & 0xFFu, (packed >> 8) & 0xFFu,
                (packed >> 16) & 0xFFu, packed >> 24 };
    __builtin_nontemporal_store(v, (u32x4*)p);
}

__global__ __launch_bounds__(256)
void residual_binary_kernel(const int* __restrict__ x,
                            const int* __restrict__ w1, const int* __restrict__ w2,
                            const int* __restrict__ b1, const int* __restrict__ b2,
                            int* __restrict__ out)
{
    __shared__ u32 Ts[2][WORDS];
    const int t = threadIdx.x;

    // packed row-invariant constants at this thread's own words 2t+512q (+j)
    u32 B1w[4][2], C1w[4][2], M2w[4][2], C2w[4][2];
#pragma unroll
    for (int q = 0; q < 4; ++q) {
        const int e = 4 * (2 * t + 512 * q);   // element base (8 elements)
#pragma unroll
        for (int j = 0; j < 2; ++j) {
            u32 pb1 = pack4(*(const u32x4*)(b1 + e + 4 * j));
            u32 pw1 = pack4(*(const u32x4*)(w1 + e + 4 * j));
            u32 pb2 = pack4(*(const u32x4*)(b2 + e + 4 * j));
            u32 pw2 = pack4(*(const u32x4*)(w2 + e + 4 * j));
            B1w[q][j] = pb1;  C1w[q][j] = (~pw1) & pb1;
            M2w[q][j] = ~pb2; C2w[q][j] = ((~pw2) & (~pb2)) | pb2;
        }
    }

    const u32 sel_even = 0x06040200u;
    const u32 sel_odd  = 0x07050301u;

    const long long row0 = (long long)blockIdx.x * RPB;

    // prefetch row 0 (r==0 -> temporal)
    u32x4 P[8];
    {
        const int* xr = x + row0 * (long long)W;
#pragma unroll
        for (int k = 0; k < 8; ++k)
            P[k] = *(const u32x4*)(xr + 8 * t + 2048 * (k >> 1) + 4 * (k & 1));
    }

#pragma unroll
    for (int r = 0; r < RPB; ++r) {
        const int buf = r & 1;
        int* orow = out + (row0 + r) * (long long)W;

        // pack current row into registers
        u32 X[4][2];
#pragma unroll
        for (int q = 0; q < 4; ++q) {
            X[q][0] = pack4(P[2 * q]);
            X[q][1] = pack4(P[2 * q + 1]);
        }

        // issue next row's loads (NT for the last row of the group)
        if (r + 1 < RPB) {
            const int* xn = x + (row0 + r + 1) * (long long)W;
            if (r + 1 == 3) {
#pragma unroll
                for (int k = 0; k < 8; ++k)
                    P[k] = __builtin_nontemporal_load(
                        (const u32x4*)(xn + 8 * t + 2048 * (k >> 1) + 4 * (k & 1)));
            } else {
#pragma unroll
                for (int k = 0; k < 8; ++k)
                    P[k] = *(const u32x4*)(xn + 8 * t + 2048 * (k >> 1) + 4 * (k & 1));
            }
        }

        // stage 1 (register-local): y = x | swap(z1); transpose -> Ts
#pragma unroll
        for (int q = 0; q < 4; ++q) {
            const int p = q ^ 2;   // swap partner run
            u32 y0 = X[q][0] | ((X[p][0] & B1w[p][0]) ^ C1w[p][0]);
            u32 y1 = X[q][1] | ((X[p][1] & B1w[p][1]) ^ C1w[p][1]);
            const int K = t + 256 * q;
            Ts[buf][K]        = perm_b32(y1, y0, sel_even);
            Ts[buf][K + HALF] = perm_b32(y1, y0, sel_odd);
        }

        __syncthreads();   // Ts[buf] ready

        // stage 2: u = T & swap(z2); transpose -> out (NT store, unpacked)
        u32 Ta[4][2];
#pragma unroll
        for (int q = 0; q < 4; ++q) {
            uint2 v = *(const uint2*)&Ts[buf][2 * t + 512 * q];
            Ta[q][0] = v.x;  Ta[q][1] = v.y;
        }
#pragma unroll
        for (int q = 0; q < 4; ++q) {
            const int p = q ^ 2;
            u32 u0 = Ta[q][0] & ((Ta[p][0] & M2w[p][0]) ^ C2w[p][0]);
            u32 u1 = Ta[q][1] & ((Ta[p][1] & M2w[p][1]) ^ C2w[p][1]);
            const int K = t + 256 * q;
            nt_store4(orow + 4 * K,          perm_b32(u1, u0, sel_even));
            nt_store4(orow + 4 * (K + HALF), perm_b32(u1, u0, sel_odd));
        }
        // no trailing barrier: Ts is double-buffered; a wave's buf reads
        // complete before it reaches the next iteration's barrier.
    }
}

extern "C" void kernel_launch(void* const* d_in, const int* in_sizes, int n_in,
                              void* d_out, int out_size, void* d_ws, size_t ws_size,
                              hipStream_t stream) {
    const int* x  = (const int*)d_in[0];
    const int* w1 = (const int*)d_in[1];
    const int* w2 = (const int*)d_in[2];
    const int* b1 = (const int*)d_in[3];
    const int* b2 = (const int*)d_in[4];
    int* out = (int*)d_out;

    const int rows = in_sizes[0] / W;   // 8192
    const int grid = rows / RPB;        // 2048 blocks x 256 threads
    residual_binary_kernel<<<grid, 256, 0, stream>>>(x, w1, w2, b1, b2, out);
}

// Round 6
// 84.903 us; speedup vs baseline: 1.4215x; 1.0050x over previous
//
#include <hip/hip_runtime.h>

// Residual_Binary — fused single-pass, thread-local stage 1, ONE barrier/row.
// (Revert of the failed sc1-bypass probe; this is the R4 kernel that ran at
// 6.29 TB/s effective — exactly the measured mixed-stream HBM ceiling.)
//
// Index algebra (byte j, 13 bits): swap j->j^4096 (packed word m -> m^1024);
// transpose2 = even/odd byte de-interleave = one v_perm_b32 per output word.
// Thread t owns words m = 2t+512q (q=0..3); m^1024 = 2t+512(q^2) is the SAME
// thread's word -> stage-1 swap+xnor is register-local. Only the second
// transpose crosses threads (Ts in LDS, double-buffered, 1 barrier/row).
//
// Identities (w1,w2,b1,b2 bytes in {0,255}):
//   z1 = (~(x^w1))&0xFF & b1 = (x & B1)^C1,  B1=b1, C1=(~w1)&b1
//   z2 = ((~(t^w2))&0xFF)|b2 = (t & M2)^C2,  M2=~b2, C2=((~w2)&~b2)|b2
//
// LLC management: out (write-once) uses __builtin_nontemporal_store (L2
// no-allocate, stays coherent); 25% of x rows (r==3) use nontemporal loads.

constexpr int W     = 8192;
constexpr int WORDS = 2048;
constexpr int HALF  = 1024;
constexpr int RPB   = 4;

typedef unsigned u32;
typedef u32 u32x4 __attribute__((ext_vector_type(4)));

static __device__ __forceinline__ u32 perm_b32(u32 hi, u32 lo, u32 sel) {
    return __builtin_amdgcn_perm(hi, lo, sel);
}

static __device__ __forceinline__ u32 pack4(u32x4 v) {
    return (v[0] & 0xFFu) | ((v[1] & 0xFFu) << 8) | ((v[2] & 0xFFu) << 16) | ((v[3] & 0xFFu) << 24);
}

static __device__ __forceinline__ void nt_store4(int* p, u32 packed) {
    u32x4 v = { packed & 0xFFu, (packed >> 8) & 0xFFu,
                (packed >> 16) & 0xFFu, packed >> 24 };
    __builtin_nontemporal_store(v, (u32x4*)p);
}

__global__ __launch_bounds__(256)
void residual_binary_kernel(const int* __restrict__ x,
                            const int* __restrict__ w1, const int* __restrict__ w2,
                            const int* __restrict__ b1, const int* __restrict__ b2,
                            int* __restrict__ out)
{
    __shared__ u32 Ts[2][WORDS];
    const int t = threadIdx.x;

    // packed row-invariant constants at this thread's own words 2t+512q (+j)
    u32 B1w[4][2], C1w[4][2], M2w[4][2], C2w[4][2];
#pragma unroll
    for (int q = 0; q < 4; ++q) {
        const int e = 4 * (2 * t + 512 * q);   // element base (8 elements)
#pragma unroll
        for (int j = 0; j < 2; ++j) {
            u32 pb1 = pack4(*(const u32x4*)(b1 + e + 4 * j));
            u32 pw1 = pack4(*(const u32x4*)(w1 + e + 4 * j));
            u32 pb2 = pack4(*(const u32x4*)(b2 + e + 4 * j));
            u32 pw2 = pack4(*(const u32x4*)(w2 + e + 4 * j));
            B1w[q][j] = pb1;  C1w[q][j] = (~pw1) & pb1;
            M2w[q][j] = ~pb2; C2w[q][j] = ((~pw2) & (~pb2)) | pb2;
        }
    }

    const u32 sel_even = 0x06040200u;
    const u32 sel_odd  = 0x07050301u;

    const long long row0 = (long long)blockIdx.x * RPB;

    // prefetch row 0 (temporal)
    u32x4 P[8];
    {
        const int* xr = x + row0 * (long long)W;
#pragma unroll
        for (int k = 0; k < 8; ++k)
            P[k] = *(const u32x4*)(xr + 8 * t + 2048 * (k >> 1) + 4 * (k & 1));
    }

#pragma unroll
    for (int r = 0; r < RPB; ++r) {
        const int buf = r & 1;
        int* orow = out + (row0 + r) * (long long)W;

        // pack current row into registers
        u32 X[4][2];
#pragma unroll
        for (int q = 0; q < 4; ++q) {
            X[q][0] = pack4(P[2 * q]);
            X[q][1] = pack4(P[2 * q + 1]);
        }

        // issue next row's loads (NT for the last row of the group)
        if (r + 1 < RPB) {
            const int* xn = x + (row0 + r + 1) * (long long)W;
            if (r + 1 == 3) {
#pragma unroll
                for (int k = 0; k < 8; ++k)
                    P[k] = __builtin_nontemporal_load(
                        (const u32x4*)(xn + 8 * t + 2048 * (k >> 1) + 4 * (k & 1)));
            } else {
#pragma unroll
                for (int k = 0; k < 8; ++k)
                    P[k] = *(const u32x4*)(xn + 8 * t + 2048 * (k >> 1) + 4 * (k & 1));
            }
        }

        // stage 1 (register-local): y = x | swap(z1); transpose -> Ts
#pragma unroll
        for (int q = 0; q < 4; ++q) {
            const int p = q ^ 2;   // swap partner run
            u32 y0 = X[q][0] | ((X[p][0] & B1w[p][0]) ^ C1w[p][0]);
            u32 y1 = X[q][1] | ((X[p][1] & B1w[p][1]) ^ C1w[p][1]);
            const int K = t + 256 * q;
            Ts[buf][K]        = perm_b32(y1, y0, sel_even);
            Ts[buf][K + HALF] = perm_b32(y1, y0, sel_odd);
        }

        __syncthreads();   // Ts[buf] ready

        // stage 2: u = T & swap(z2); transpose -> out (NT store, unpacked)
        u32 Ta[4][2];
#pragma unroll
        for (int q = 0; q < 4; ++q) {
            uint2 v = *(const uint2*)&Ts[buf][2 * t + 512 * q];
            Ta[q][0] = v.x;  Ta[q][1] = v.y;
        }
#pragma unroll
        for (int q = 0; q < 4; ++q) {
            const int p = q ^ 2;
            u32 u0 = Ta[q][0] & ((Ta[p][0] & M2w[p][0]) ^ C2w[p][0]);
            u32 u1 = Ta[q][1] & ((Ta[p][1] & M2w[p][1]) ^ C2w[p][1]);
            const int K = t + 256 * q;
            nt_store4(orow + 4 * K,          perm_b32(u1, u0, sel_even));
            nt_store4(orow + 4 * (K + HALF), perm_b32(u1, u0, sel_odd));
        }
        // no trailing barrier: Ts is double-buffered; a wave's buf reads
        // complete before it reaches the next iteration's barrier.
    }
}

extern "C" void kernel_launch(void* const* d_in, const int* in_sizes, int n_in,
                              void* d_out, int out_size, void* d_ws, size_t ws_size,
                              hipStream_t stream) {
    const int* x  = (const int*)d_in[0];
    const int* w1 = (const int*)d_in[1];
    const int* w2 = (const int*)d_in[2];
    const int* b1 = (const int*)d_in[3];
    const int* b2 = (const int*)d_in[4];
    int* out = (int*)d_out;

    const int rows = in_sizes[0] / W;   // 8192
    const int grid = rows / RPB;        // 2048 blocks x 256 threads
    residual_binary_kernel<<<grid, 256, 0, stream>>>(x, w1, w2, b1, b2, out);
}